// Round 1
// baseline (531.374 us; speedup 1.0000x reference)
//
#include <hip/hip_runtime.h>
#include <math.h>

#define NL 24
#define BB 16
#define HH 32
#define DD 64
#define EE 2048
#define TSH 32
#define NB 5
#define BE (BB*EE)            /* 32768  */
#define STATE_N (NL*BB*EE)    /* 786432 */
#define SM_N (NL*BB*HH*DD*DD) /* 50331648 */
#define GN_EPS 1e-3f

// ---------------- init: time_mixed <- out_b, g <- gate_b ----------------
__global__ void k_init(float* out_tm, float* g, const float* __restrict__ out_b,
                       const float* __restrict__ gate_b) {
    int idx = blockIdx.x * 256 + threadIdx.x;   // 65536 total
    if (idx < BE) out_tm[idx] = out_b[idx & (EE - 1)];
    else {
        int j = idx - BE;
        g[j] = gate_b[j & (EE - 1)];
    }
}

// ---------------- new_state: copy state, replace layer slice with inputs ----
__global__ void k_copy_state(const float4* __restrict__ state4,
                             const float4* __restrict__ inputs4,
                             float4* __restrict__ out4, const int* __restrict__ lid_p) {
    int i = blockIdx.x * 256 + threadIdx.x;     // 196608 float4
    int lid = *lid_p;
    int lo = lid * (BE / 4);
    float4 v;
    if (i >= lo && i < lo + BE / 4) v = inputs4[i - lo];
    else v = state4[i];
    out4[i] = v;
}

// ---------------- new_state_matrix passthrough copy (layer slice fixed later)
__global__ void k_copy_sm(const float4* __restrict__ sm4, float4* __restrict__ out4) {
    int i = blockIdx.x * 256 + threadIdx.x;     // 12582912 float4
    out4[i] = sm4[i];
}

// ---------------- hdn[s,b,h] = tanh(lora_in . Aw + Ab) ----------------
__global__ void k_hdn(const float* __restrict__ inputs, const float* __restrict__ state,
                      const float* __restrict__ mus, const float* __restrict__ Aw,
                      const float* __restrict__ Ab, float* __restrict__ hdn,
                      const int* __restrict__ lid_p) {
    int s = blockIdx.x / BB, b = blockIdx.x % BB;
    int tid = threadIdx.x;
    int lid = *lid_p;
    __shared__ float li[EE];
    const float* x  = inputs + b * EE;
    const float* lx = state + lid * BE + b * EE;
    const float* mu = mus + s * EE;
    for (int e = tid; e < EE; e += 256) {
        float xv = x[e];
        li[e] = xv + (xv - lx[e]) * mu[e];
    }
    __syncthreads();
    int h = tid & 31, part = tid >> 5;          // 8 parts x 256 elems
    const float* A = Aw + s * EE * TSH;
    float acc = 0.f;
    int e0 = part * 256;
    for (int e = e0; e < e0 + 256; ++e) acc += li[e] * A[e * TSH + h];
    __shared__ float red[32][9];
    red[h][part] = acc;
    __syncthreads();
    if (tid < 32) {
        float sum = Ab[s * TSH + tid];
        #pragma unroll
        for (int p = 0; p < 8; ++p) sum += red[tid][p];
        hdn[(s * BB + b) * TSH + tid] = tanhf(sum);
    }
}

// ---------------- ts = (hdn@Bw + Bb + lambda)*diff + x ; also gx ----------
__global__ void k_ts(const float* __restrict__ inputs, const float* __restrict__ state,
                     const float* __restrict__ lambdas, const float* __restrict__ Bw,
                     const float* __restrict__ Bb, const float* __restrict__ hdn,
                     const float* __restrict__ gate_mu, float* __restrict__ ts,
                     float* __restrict__ gx, const int* __restrict__ lid_p) {
    int idx = blockIdx.x * 256 + threadIdx.x;   // NB*BE
    int s = idx / BE, r = idx % BE;
    int b = r / EE, e = r % EE;
    int lid = *lid_p;
    const float* hp = hdn + (s * BB + b) * TSH;
    const float* Bp = Bw + s * TSH * EE + e;
    float acc = Bb[s * EE + e] + lambdas[s * EE + e];
    #pragma unroll
    for (int h = 0; h < TSH; ++h) acc += hp[h] * Bp[h * EE];
    float xv = inputs[r];
    float lxv = state[lid * BE + r];
    ts[idx] = acc * (xv - lxv) + xv;
    if (s == 0) {
        float gm = gate_mu[e];
        gx[r] = xv * gm + lxv * (1.f - gm);
    }
}

// ---------------- per-head dense: proj[s,b,h,e] = ts[s,b,h,:]@MW[s,h,:,e]+Mb
__global__ void k_proj(const float* __restrict__ ts, const float* __restrict__ MW,
                       const float* __restrict__ Mb, float* __restrict__ proj) {
    int bi = blockIdx.x;                        // NB*BB*HH
    int s = bi / (BB * HH), r = bi % (BB * HH);
    int b = r / HH, h = r % HH;
    int e = threadIdx.x;                        // 64
    const float* t = ts + ((s * BB + b) * HH + h) * DD;
    __shared__ float tl[DD];
    tl[e] = t[e];
    __syncthreads();
    const float* M = MW + (s * HH + h) * DD * DD;
    float acc = Mb[(s * HH + h) * DD + e];
    #pragma unroll 8
    for (int d = 0; d < DD; ++d) acc += tl[d] * M[d * DD + e];
    proj[((s * BB + b) * HH + h) * DD + e] = acc;
}

// ---------------- out[b,e] += sum_k A[b,k]*W[k,e]  (K split, atomics) ------
__global__ void k_mm_atomic(const float* __restrict__ Arows, const float* __restrict__ W,
                            float* out) {
    int et = blockIdx.x & 7, kc = blockIdx.x >> 3;   // 8 e-tiles x 8 k-chunks
    int tid = threadIdx.x;
    int e = et * 256 + tid;
    int k0 = kc * 256;
    __shared__ float al[BB][256];
    for (int i = tid; i < BB * 256; i += 256) {
        int b = i >> 8, ee = i & 255;
        al[b][ee] = Arows[b * EE + k0 + ee];
    }
    __syncthreads();
    float acc[BB];
    #pragma unroll
    for (int b = 0; b < BB; ++b) acc[b] = 0.f;
    for (int ee = 0; ee < 256; ++ee) {
        float wv = W[(k0 + ee) * EE + e];
        #pragma unroll
        for (int b = 0; b < BB; ++b) acc[b] += al[b][ee] * wv;
    }
    #pragma unroll
    for (int b = 0; b < BB; ++b) atomicAdd(&out[b * EE + e], acc[b]);
}

// ---------------- RWKV state update + groupnorm + gated activation --------
__global__ void k_rwkv(const float* __restrict__ proj, const float* __restrict__ state_matrix,
                       const float* __restrict__ g, const float* __restrict__ gn_gamma,
                       const float* __restrict__ gn_beta, float* __restrict__ out_sm,
                       float* __restrict__ a_out, const int* __restrict__ lid_p) {
    int bi = blockIdx.x;                        // BB*HH
    int b = bi / HH, h = bi % HH;
    int j = threadIdx.x;                        // 64
    int lid = *lid_p;
    const float* P = proj + (b * HH + h) * DD + j;
    float kv   = P[0 * BE];
    float rv   = P[1 * BE];
    float wraw = P[2 * BE];
    float vv   = P[3 * BE];
    float uv   = P[4 * BE];
    float wv = expf(-expf(wraw));
    float vr = vv * rv;
    #pragma unroll
    for (int o = 32; o; o >>= 1) vr += __shfl_xor(vr, o);
    __shared__ float kA[DD], wA[DD], uA[DD], rw[DD];
    kA[j] = kv; wA[j] = wv; uA[j] = uv;
    __syncthreads();
    int base = ((lid * BB + b) * HH + h) * DD * DD;
    const float* S = state_matrix + base;
    float* NS = out_sm + base;
    for (int i = 0; i < DD; ++i) {
        float sij = S[i * DD + j];
        NS[i * DD + j] = wA[i] * sij + kA[i] * vv;
        float p = sij * rv;
        #pragma unroll
        for (int o = 32; o; o >>= 1) p += __shfl_xor(p, o);
        if (j == 0) rw[i] = kA[i] * uA[i] * vr + p;
    }
    __syncthreads();
    float x = rw[j];
    float m = x;
    #pragma unroll
    for (int o = 32; o; o >>= 1) m += __shfl_xor(m, o);
    m *= (1.f / 64.f);
    float d = x - m;
    float var = d * d;
    #pragma unroll
    for (int o = 32; o; o >>= 1) var += __shfl_xor(var, o);
    var *= (1.f / 64.f);
    float normed = d * rsqrtf(var + GN_EPS);
    int e = h * DD + j;
    float ng = normed * gn_gamma[e] + gn_beta[e];
    float gval = g[b * EE + e];
    float silu = gval / (1.f + expf(-gval));
    a_out[b * EE + e] = ng * silu;
}

extern "C" void kernel_launch(void* const* d_in, const int* in_sizes, int n_in,
                              void* d_out, int out_size, void* d_ws, size_t ws_size,
                              hipStream_t stream) {
    const float* inputs   = (const float*)d_in[0];
    const float* state    = (const float*)d_in[1];
    const float* sm       = (const float*)d_in[2];
    const float* mus      = (const float*)d_in[3];
    const float* lambdas  = (const float*)d_in[4];
    const float* Aw       = (const float*)d_in[5];
    const float* Ab       = (const float*)d_in[6];
    const float* Bw       = (const float*)d_in[7];
    const float* Bb       = (const float*)d_in[8];
    const float* MW       = (const float*)d_in[9];
    const float* Mb       = (const float*)d_in[10];
    const float* gate_mu  = (const float*)d_in[11];
    const float* gate_W   = (const float*)d_in[12];
    const float* gate_b   = (const float*)d_in[13];
    const float* gn_gamma = (const float*)d_in[14];
    const float* gn_beta  = (const float*)d_in[15];
    const float* out_W    = (const float*)d_in[16];
    const float* out_b    = (const float*)d_in[17];
    const int*   lid      = (const int*)d_in[18];

    float* out_tm    = (float*)d_out;
    float* out_state = out_tm + BE;
    float* out_sm    = out_state + STATE_N;

    float* ws   = (float*)d_ws;
    float* ts   = ws;                       // NB*BE
    float* proj = ts + NB * BE;             // NB*BE
    float* hdn  = proj + NB * BE;           // NB*BB*TSH
    float* gx   = hdn + NB * BB * TSH;      // BE
    float* g    = gx + BE;                  // BE
    float* a    = g + BE;                   // BE

    k_init<<<(2 * BE) / 256, 256, 0, stream>>>(out_tm, g, out_b, gate_b);
    k_copy_state<<<(STATE_N / 4) / 256, 256, 0, stream>>>(
        (const float4*)state, (const float4*)inputs, (float4*)out_state, lid);
    k_copy_sm<<<(SM_N / 4) / 256, 256, 0, stream>>>(
        (const float4*)sm, (float4*)out_sm);
    k_hdn<<<NB * BB, 256, 0, stream>>>(inputs, state, mus, Aw, Ab, hdn, lid);
    k_ts<<<(NB * BE) / 256, 256, 0, stream>>>(inputs, state, lambdas, Bw, Bb, hdn,
                                              gate_mu, ts, gx, lid);
    k_proj<<<NB * BB * HH, 64, 0, stream>>>(ts, MW, Mb, proj);
    k_mm_atomic<<<64, 256, 0, stream>>>(gx, gate_W, g);
    k_rwkv<<<BB * HH, 64, 0, stream>>>(proj, sm, g, gn_gamma, gn_beta, out_sm, a, lid);
    k_mm_atomic<<<64, 256, 0, stream>>>(a, out_W, out_tm);
}

// Round 2
// 464.445 us; speedup vs baseline: 1.1441x; 1.1441x over previous
//
#include <hip/hip_runtime.h>
#include <math.h>

#define NL 24
#define BB 16
#define HH 32
#define DD 64
#define EE 2048
#define TSH 32
#define NB 5
#define BE (BB*EE)            /* 32768  */
#define STATE_N (NL*BB*EE)    /* 786432 */
#define SM_N (NL*BB*HH*DD*DD) /* 50331648 */
#define GN_EPS 1e-3f

// ---------------- init: time_mixed <- out_b, g <- gate_b ----------------
__global__ void k_init(float* out_tm, float* g, const float* __restrict__ out_b,
                       const float* __restrict__ gate_b) {
    int idx = blockIdx.x * 256 + threadIdx.x;   // 65536 total
    if (idx < BE) out_tm[idx] = out_b[idx & (EE - 1)];
    else {
        int j = idx - BE;
        g[j] = gate_b[j & (EE - 1)];
    }
}

// ---------------- new_state: copy state, replace layer slice with inputs ----
__global__ void k_copy_state(const float4* __restrict__ state4,
                             const float4* __restrict__ inputs4,
                             float4* __restrict__ out4, const int* __restrict__ lid_p) {
    int i = blockIdx.x * 256 + threadIdx.x;     // 196608 float4
    int lid = *lid_p;
    int lo = lid * (BE / 4);
    float4 v;
    if (i >= lo && i < lo + BE / 4) v = inputs4[i - lo];
    else v = state4[i];
    out4[i] = v;
}

// ---------------- hdn[s,b,h] = tanh(lora_in . Aw + Ab) ----------------
__global__ void k_hdn(const float* __restrict__ inputs, const float* __restrict__ state,
                      const float* __restrict__ mus, const float* __restrict__ Aw,
                      const float* __restrict__ Ab, float* __restrict__ hdn,
                      const int* __restrict__ lid_p) {
    int s = blockIdx.x / BB, b = blockIdx.x % BB;
    int tid = threadIdx.x;
    int lid = *lid_p;
    __shared__ float li[EE];
    const float* x  = inputs + b * EE;
    const float* lx = state + lid * BE + b * EE;
    const float* mu = mus + s * EE;
    for (int e = tid; e < EE; e += 256) {
        float xv = x[e];
        li[e] = xv + (xv - lx[e]) * mu[e];
    }
    __syncthreads();
    int h = tid & 31, part = tid >> 5;          // 8 parts x 256 elems
    const float* A = Aw + s * EE * TSH;
    float acc = 0.f;
    int e0 = part * 256;
    for (int e = e0; e < e0 + 256; ++e) acc += li[e] * A[e * TSH + h];
    __shared__ float red[32][9];
    red[h][part] = acc;
    __syncthreads();
    if (tid < 32) {
        float sum = Ab[s * TSH + tid];
        #pragma unroll
        for (int p = 0; p < 8; ++p) sum += red[tid][p];
        hdn[(s * BB + b) * TSH + tid] = tanhf(sum);
    }
}

// ---------------- ts = (hdn@Bw + Bb + lambda)*diff + x ; also gx ----------
__global__ void k_ts(const float* __restrict__ inputs, const float* __restrict__ state,
                     const float* __restrict__ lambdas, const float* __restrict__ Bw,
                     const float* __restrict__ Bb, const float* __restrict__ hdn,
                     const float* __restrict__ gate_mu, float* __restrict__ ts,
                     float* __restrict__ gx, const int* __restrict__ lid_p) {
    int idx = blockIdx.x * 256 + threadIdx.x;   // NB*BE
    int s = idx / BE, r = idx % BE;
    int b = r / EE, e = r % EE;
    int lid = *lid_p;
    const float* hp = hdn + (s * BB + b) * TSH;
    const float* Bp = Bw + s * TSH * EE + e;
    float acc = Bb[s * EE + e] + lambdas[s * EE + e];
    #pragma unroll
    for (int h = 0; h < TSH; ++h) acc += hp[h] * Bp[h * EE];
    float xv = inputs[r];
    float lxv = state[lid * BE + r];
    ts[idx] = acc * (xv - lxv) + xv;
    if (s == 0) {
        float gm = gate_mu[e];
        gx[r] = xv * gm + lxv * (1.f - gm);
    }
}

// ---------------- per-head dense: proj[s,b,h,e] = ts[s,b,h,:]@MW[s,h,:,e]+Mb
__global__ void k_proj(const float* __restrict__ ts, const float* __restrict__ MW,
                       const float* __restrict__ Mb, float* __restrict__ proj) {
    int bi = blockIdx.x;                        // NB*BB*HH
    int s = bi / (BB * HH), r = bi % (BB * HH);
    int b = r / HH, h = r % HH;
    int e = threadIdx.x;                        // 64
    const float* t = ts + ((s * BB + b) * HH + h) * DD;
    __shared__ float tl[DD];
    tl[e] = t[e];
    __syncthreads();
    const float* M = MW + (s * HH + h) * DD * DD;
    float acc = Mb[(s * HH + h) * DD + e];
    #pragma unroll 8
    for (int d = 0; d < DD; ++d) acc += tl[d] * M[d * DD + e];
    proj[((s * BB + b) * HH + h) * DD + e] = acc;
}

// ---------------- out[b,e] += sum_k A[b,k]*W[k,e]  (K split, atomics) ------
// grid 256 = 16 e-tiles(128) x 16 k-chunks(128), 128 threads
__global__ void k_mm(const float* __restrict__ Arows, const float* __restrict__ W,
                     float* out) {
    int et = blockIdx.x & 15, kc = blockIdx.x >> 4;
    int tid = threadIdx.x;
    int e = et * 128 + tid;
    int k0 = kc * 128;
    __shared__ float al[BB][128];
    for (int i = tid; i < BB * 128; i += 128) {
        int b = i >> 7, kk = i & 127;
        al[b][kk] = Arows[b * EE + k0 + kk];
    }
    __syncthreads();
    float acc[BB];
    #pragma unroll
    for (int b = 0; b < BB; ++b) acc[b] = 0.f;
    for (int kk = 0; kk < 128; ++kk) {
        float wv = W[(k0 + kk) * EE + e];
        #pragma unroll
        for (int b = 0; b < BB; ++b) acc[b] += al[b][kk] * wv;
    }
    #pragma unroll
    for (int b = 0; b < BB; ++b) atomicAdd(&out[b * EE + e], acc[b]);
}

// -------- fused: state_matrix passthrough copy + RWKV update + groupnorm ----
// grid NL*BB*HH blocks x 256 threads. Non-lid layers: float4 copy.
// Lid layer: 4 waves, 16 rows each, 4 interleaved butterfly reductions.
__global__ void k_sm_rwkv(const float4* __restrict__ sm4, float4* __restrict__ out4,
                          const float* __restrict__ proj, const float* __restrict__ g,
                          const float* __restrict__ gn_gamma, const float* __restrict__ gn_beta,
                          float* __restrict__ a_out, const int* __restrict__ lid_p) {
    int blk = blockIdx.x;                       // NL*BB*HH = 12288
    int tid = threadIdx.x;                      // 256
    int lid = *lid_p;
    int layer = blk / (BB * HH);
    int base4 = blk * (DD * DD / 4);            // 1024 float4 per head
    if (layer != lid) {
        const float4* src = sm4 + base4;
        float4* dst = out4 + base4;
        #pragma unroll
        for (int p = 0; p < 4; ++p) dst[p * 256 + tid] = src[p * 256 + tid];
        return;
    }
    int r = blk % (BB * HH);
    int b = r / HH, h = r % HH;
    int j = tid & 63, q = tid >> 6;
    const float* P = proj + (b * HH + h) * DD + j;
    float kv   = P[0 * BE];
    float rv   = P[1 * BE];
    float wraw = P[2 * BE];
    float vv   = P[3 * BE];
    float uv   = P[4 * BE];
    float wv = expf(-expf(wraw));
    float vr = vv * rv;
    #pragma unroll
    for (int o = 32; o; o >>= 1) vr += __shfl_xor(vr, o);
    __shared__ float rw[DD];
    const float* S = (const float*)(sm4 + base4);
    float* NS = (float*)(out4 + base4);
    for (int ii = 0; ii < 16; ii += 4) {
        int i0 = q * 16 + ii;
        float sv[4], kk[4], ww[4], uu[4], pp[4];
        #pragma unroll
        for (int t = 0; t < 4; ++t) {
            sv[t] = S[(i0 + t) * DD + j];
            kk[t] = __shfl(kv, i0 + t);
            ww[t] = __shfl(wv, i0 + t);
            uu[t] = __shfl(uv, i0 + t);
        }
        #pragma unroll
        for (int t = 0; t < 4; ++t) {
            NS[(i0 + t) * DD + j] = ww[t] * sv[t] + kk[t] * vv;
            pp[t] = sv[t] * rv;
        }
        #pragma unroll
        for (int o = 32; o; o >>= 1) {
            #pragma unroll
            for (int t = 0; t < 4; ++t) pp[t] += __shfl_xor(pp[t], o);
        }
        if (j == 0) {
            #pragma unroll
            for (int t = 0; t < 4; ++t) rw[i0 + t] = kk[t] * uu[t] * vr + pp[t];
        }
    }
    __syncthreads();
    if (tid < DD) {
        float x = rw[tid];
        float m = x;
        #pragma unroll
        for (int o = 32; o; o >>= 1) m += __shfl_xor(m, o);
        m *= (1.f / 64.f);
        float d = x - m;
        float var = d * d;
        #pragma unroll
        for (int o = 32; o; o >>= 1) var += __shfl_xor(var, o);
        var *= (1.f / 64.f);
        float normed = d * rsqrtf(var + GN_EPS);
        int e = h * DD + tid;
        float ng = normed * gn_gamma[e] + gn_beta[e];
        float gval = g[b * EE + e];
        float silu = gval / (1.f + expf(-gval));
        a_out[b * EE + e] = ng * silu;
    }
}

extern "C" void kernel_launch(void* const* d_in, const int* in_sizes, int n_in,
                              void* d_out, int out_size, void* d_ws, size_t ws_size,
                              hipStream_t stream) {
    const float* inputs   = (const float*)d_in[0];
    const float* state    = (const float*)d_in[1];
    const float* sm       = (const float*)d_in[2];
    const float* mus      = (const float*)d_in[3];
    const float* lambdas  = (const float*)d_in[4];
    const float* Aw       = (const float*)d_in[5];
    const float* Ab       = (const float*)d_in[6];
    const float* Bw       = (const float*)d_in[7];
    const float* Bb       = (const float*)d_in[8];
    const float* MW       = (const float*)d_in[9];
    const float* Mb       = (const float*)d_in[10];
    const float* gate_mu  = (const float*)d_in[11];
    const float* gate_W   = (const float*)d_in[12];
    const float* gate_b   = (const float*)d_in[13];
    const float* gn_gamma = (const float*)d_in[14];
    const float* gn_beta  = (const float*)d_in[15];
    const float* out_W    = (const float*)d_in[16];
    const float* out_b    = (const float*)d_in[17];
    const int*   lid      = (const int*)d_in[18];

    float* out_tm    = (float*)d_out;
    float* out_state = out_tm + BE;
    float* out_sm    = out_state + STATE_N;

    float* ws   = (float*)d_ws;
    float* ts   = ws;                       // NB*BE
    float* proj = ts + NB * BE;             // NB*BE
    float* hdn  = proj + NB * BE;           // NB*BB*TSH
    float* gx   = hdn + NB * BB * TSH;      // BE
    float* g    = gx + BE;                  // BE
    float* a    = g + BE;                   // BE

    k_init<<<(2 * BE) / 256, 256, 0, stream>>>(out_tm, g, out_b, gate_b);
    k_copy_state<<<(STATE_N / 4) / 256, 256, 0, stream>>>(
        (const float4*)state, (const float4*)inputs, (float4*)out_state, lid);
    k_hdn<<<NB * BB, 256, 0, stream>>>(inputs, state, mus, Aw, Ab, hdn, lid);
    k_ts<<<(NB * BE) / 256, 256, 0, stream>>>(inputs, state, lambdas, Bw, Bb, hdn,
                                              gate_mu, ts, gx, lid);
    k_proj<<<NB * BB * HH, 64, 0, stream>>>(ts, MW, Mb, proj);
    k_mm<<<256, 128, 0, stream>>>(gx, gate_W, g);
    k_sm_rwkv<<<NL * BB * HH, 256, 0, stream>>>(
        (const float4*)sm, (float4*)out_sm, proj, g, gn_gamma, gn_beta, a, lid);
    k_mm<<<256, 128, 0, stream>>>(a, out_W, out_tm);
}

// Round 3
// 441.847 us; speedup vs baseline: 1.2026x; 1.0511x over previous
//
#include <hip/hip_runtime.h>
#include <math.h>

#define NL 24
#define BB 16
#define HH 32
#define DD 64
#define EE 2048
#define TSH 32
#define NB 5
#define BE (BB*EE)            /* 32768  */
#define STATE_N (NL*BB*EE)    /* 786432 */
#define SM_N (NL*BB*HH*DD*DD) /* 50331648 */
#define GN_EPS 1e-3f

// ---- prep: new_state copy (w/ layer slice = inputs) + bias-init of out_tm, g
__global__ void k_prep(const float4* __restrict__ state4, const float4* __restrict__ inputs4,
                       float4* __restrict__ out4, const int* __restrict__ lid_p,
                       float* __restrict__ out_tm, float* __restrict__ g,
                       const float* __restrict__ out_b, const float* __restrict__ gate_b) {
    int blk = blockIdx.x, tid = threadIdx.x;
    if (blk < 768) {                            // 196608 float4 state copy
        int i = blk * 256 + tid;
        int lid = *lid_p;
        int lo = lid * (BE / 4);
        float4 v = (i >= lo && i < lo + BE / 4) ? inputs4[i - lo] : state4[i];
        out4[i] = v;
    } else {                                    // 65536 bias inits
        int idx = (blk - 768) * 256 + tid;
        if (idx < BE) out_tm[idx] = out_b[idx & (EE - 1)];
        else g[idx - BE] = gate_b[(idx - BE) & (EE - 1)];
    }
}

// ---------------- hdn[s,b,h] = tanh(lora_in . Aw + Ab) ----------------
__global__ void k_hdn(const float* __restrict__ inputs, const float* __restrict__ state,
                      const float* __restrict__ mus, const float* __restrict__ Aw,
                      const float* __restrict__ Ab, float* __restrict__ hdn,
                      const int* __restrict__ lid_p) {
    int s = blockIdx.x / BB, b = blockIdx.x % BB;
    int tid = threadIdx.x;
    int lid = *lid_p;
    __shared__ float li[EE];
    const float* x  = inputs + b * EE;
    const float* lx = state + lid * BE + b * EE;
    const float* mu = mus + s * EE;
    for (int e = tid; e < EE; e += 256) {
        float xv = x[e];
        li[e] = xv + (xv - lx[e]) * mu[e];
    }
    __syncthreads();
    int h = tid & 31, part = tid >> 5;          // 8 parts x 256 elems
    const float* A = Aw + s * EE * TSH;
    float acc = 0.f;
    int e0 = part * 256;
    for (int e = e0; e < e0 + 256; ++e) acc += li[e] * A[e * TSH + h];
    __shared__ float red[32][9];
    red[h][part] = acc;
    __syncthreads();
    if (tid < 32) {
        float sum = Ab[s * TSH + tid];
        #pragma unroll
        for (int p = 0; p < 8; ++p) sum += red[tid][p];
        hdn[(s * BB + b) * TSH + tid] = tanhf(sum);
    }
}

// ---------------- ts = (hdn@Bw + Bb + lambda)*diff + x ; also gx ----------
__global__ void k_ts(const float* __restrict__ inputs, const float* __restrict__ state,
                     const float* __restrict__ lambdas, const float* __restrict__ Bw,
                     const float* __restrict__ Bb, const float* __restrict__ hdn,
                     const float* __restrict__ gate_mu, float* __restrict__ ts,
                     float* __restrict__ gx, const int* __restrict__ lid_p) {
    int idx = blockIdx.x * 256 + threadIdx.x;   // NB*BE
    int s = idx / BE, r = idx % BE;
    int b = r / EE, e = r % EE;
    int lid = *lid_p;
    const float* hp = hdn + (s * BB + b) * TSH;
    const float* Bp = Bw + s * TSH * EE + e;
    float acc = Bb[s * EE + e] + lambdas[s * EE + e];
    #pragma unroll
    for (int h = 0; h < TSH; ++h) acc += hp[h] * Bp[h * EE];
    float xv = inputs[r];
    float lxv = state[lid * BE + r];
    ts[idx] = acc * (xv - lxv) + xv;
    if (s == 0) {
        float gm = gate_mu[e];
        gx[r] = xv * gm + lxv * (1.f - gm);
    }
}

// ------- per-head dense, 4 heads per block: proj[s,b,h,:] = ts@MW + Mb -----
__global__ void k_proj(const float* __restrict__ ts, const float* __restrict__ MW,
                       const float* __restrict__ Mb, float* __restrict__ proj) {
    int bi = blockIdx.x;                        // NB*BB*(HH/4) = 640
    int s = bi / (BB * 8);
    int r = bi % (BB * 8);
    int b = r / 8, hg = r % 8;
    int q = threadIdx.x >> 6, e = threadIdx.x & 63;
    int h = hg * 4 + q;
    __shared__ float tl[4][DD];
    tl[q][e] = ts[((s * BB + b) * HH + h) * DD + e];
    __syncthreads();
    const float* M = MW + (s * HH + h) * DD * DD;
    float acc = Mb[(s * HH + h) * DD + e];
    #pragma unroll 8
    for (int d = 0; d < DD; ++d) acc += tl[q][d] * M[d * DD + e];
    proj[((s * BB + b) * HH + h) * DD + e] = acc;
}

// ---- out[b,e] += sum_k A[b,k]*W[k,e]; A rows are block-uniform -> s_loads --
// grid 512 = 16 e-tiles(128) x 32 k-chunks(64), 128 threads
__global__ void k_mm(const float* __restrict__ Arows, const float* __restrict__ W,
                     float* out) {
    int et = blockIdx.x & 15, kc = blockIdx.x >> 4;
    int e = et * 128 + threadIdx.x;
    int k0 = kc * 64;
    float acc[BB];
    #pragma unroll
    for (int b = 0; b < BB; ++b) acc[b] = 0.f;
    #pragma unroll 4
    for (int kk = 0; kk < 64; ++kk) {
        float wv = W[(k0 + kk) * EE + e];
        #pragma unroll
        for (int b = 0; b < BB; ++b) acc[b] += Arows[b * EE + k0 + kk] * wv;
    }
    #pragma unroll
    for (int b = 0; b < BB; ++b) atomicAdd(&out[b * EE + e], acc[b]);
}

// -------- fused: state_matrix passthrough copy + RWKV update + groupnorm ----
__global__ void k_sm_rwkv(const float4* __restrict__ sm4, float4* __restrict__ out4,
                          const float* __restrict__ proj, const float* __restrict__ g,
                          const float* __restrict__ gn_gamma, const float* __restrict__ gn_beta,
                          float* __restrict__ a_out, const int* __restrict__ lid_p) {
    int blk = blockIdx.x;                       // NL*BB*HH = 12288
    int tid = threadIdx.x;                      // 256
    int lid = *lid_p;
    int layer = blk / (BB * HH);
    int base4 = blk * (DD * DD / 4);            // 1024 float4 per head
    if (layer != lid) {
        const float4* src = sm4 + base4;
        float4* dst = out4 + base4;
        #pragma unroll
        for (int p = 0; p < 4; ++p) dst[p * 256 + tid] = src[p * 256 + tid];
        return;
    }
    int r = blk % (BB * HH);
    int b = r / HH, h = r % HH;
    int j = tid & 63, q = tid >> 6;
    const float* P = proj + (b * HH + h) * DD + j;
    float kv   = P[0 * BE];
    float rv   = P[1 * BE];
    float wraw = P[2 * BE];
    float vv   = P[3 * BE];
    float uv   = P[4 * BE];
    float wv = expf(-expf(wraw));
    float vr = vv * rv;
    #pragma unroll
    for (int o = 32; o; o >>= 1) vr += __shfl_xor(vr, o);
    __shared__ float rw[DD];
    const float* S = (const float*)(sm4 + base4);
    float* NS = (float*)(out4 + base4);
    for (int ii = 0; ii < 16; ii += 4) {
        int i0 = q * 16 + ii;
        float sv[4], kk[4], ww[4], uu[4], pp[4];
        #pragma unroll
        for (int t = 0; t < 4; ++t) {
            sv[t] = S[(i0 + t) * DD + j];
            kk[t] = __shfl(kv, i0 + t);
            ww[t] = __shfl(wv, i0 + t);
            uu[t] = __shfl(uv, i0 + t);
        }
        #pragma unroll
        for (int t = 0; t < 4; ++t) {
            NS[(i0 + t) * DD + j] = ww[t] * sv[t] + kk[t] * vv;
            pp[t] = sv[t] * rv;
        }
        #pragma unroll
        for (int o = 32; o; o >>= 1) {
            #pragma unroll
            for (int t = 0; t < 4; ++t) pp[t] += __shfl_xor(pp[t], o);
        }
        if (j == 0) {
            #pragma unroll
            for (int t = 0; t < 4; ++t) rw[i0 + t] = kk[t] * uu[t] * vr + pp[t];
        }
    }
    __syncthreads();
    if (tid < DD) {
        float x = rw[tid];
        float m = x;
        #pragma unroll
        for (int o = 32; o; o >>= 1) m += __shfl_xor(m, o);
        m *= (1.f / 64.f);
        float d = x - m;
        float var = d * d;
        #pragma unroll
        for (int o = 32; o; o >>= 1) var += __shfl_xor(var, o);
        var *= (1.f / 64.f);
        float normed = d * rsqrtf(var + GN_EPS);
        int e = h * DD + tid;
        float ng = normed * gn_gamma[e] + gn_beta[e];
        float gval = g[b * EE + e];
        float silu = gval / (1.f + expf(-gval));
        a_out[b * EE + e] = ng * silu;
    }
}

extern "C" void kernel_launch(void* const* d_in, const int* in_sizes, int n_in,
                              void* d_out, int out_size, void* d_ws, size_t ws_size,
                              hipStream_t stream) {
    const float* inputs   = (const float*)d_in[0];
    const float* state    = (const float*)d_in[1];
    const float* sm       = (const float*)d_in[2];
    const float* mus      = (const float*)d_in[3];
    const float* lambdas  = (const float*)d_in[4];
    const float* Aw       = (const float*)d_in[5];
    const float* Ab       = (const float*)d_in[6];
    const float* Bw       = (const float*)d_in[7];
    const float* Bb       = (const float*)d_in[8];
    const float* MW       = (const float*)d_in[9];
    const float* Mb       = (const float*)d_in[10];
    const float* gate_mu  = (const float*)d_in[11];
    const float* gate_W   = (const float*)d_in[12];
    const float* gate_b   = (const float*)d_in[13];
    const float* gn_gamma = (const float*)d_in[14];
    const float* gn_beta  = (const float*)d_in[15];
    const float* out_W    = (const float*)d_in[16];
    const float* out_b    = (const float*)d_in[17];
    const int*   lid      = (const int*)d_in[18];

    float* out_tm    = (float*)d_out;
    float* out_state = out_tm + BE;
    float* out_sm    = out_state + STATE_N;

    float* ws   = (float*)d_ws;
    float* ts   = ws;                       // NB*BE
    float* proj = ts + NB * BE;             // NB*BE
    float* hdn  = proj + NB * BE;           // NB*BB*TSH
    float* gx   = hdn + NB * BB * TSH;      // BE
    float* g    = gx + BE;                  // BE
    float* a    = g + BE;                   // BE

    k_prep<<<1024, 256, 0, stream>>>((const float4*)state, (const float4*)inputs,
                                     (float4*)out_state, lid, out_tm, g, out_b, gate_b);
    k_hdn<<<NB * BB, 256, 0, stream>>>(inputs, state, mus, Aw, Ab, hdn, lid);
    k_ts<<<(NB * BE) / 256, 256, 0, stream>>>(inputs, state, lambdas, Bw, Bb, hdn,
                                              gate_mu, ts, gx, lid);
    k_proj<<<NB * BB * 8, 256, 0, stream>>>(ts, MW, Mb, proj);
    k_mm<<<512, 128, 0, stream>>>(gx, gate_W, g);
    k_sm_rwkv<<<NL * BB * HH, 256, 0, stream>>>(
        (const float4*)sm, (float4*)out_sm, proj, g, gn_gamma, gn_beta, a, lid);
    k_mm<<<512, 128, 0, stream>>>(a, out_W, out_tm);
}